// Round 5
// baseline (252.665 us; speedup 1.0000x reference)
//
#include <hip/hip_runtime.h>
#include <math.h>

namespace {
constexpr int S  = 2048;
constexpr int E  = 1024;
constexpr int NH = 8;
constexpr int DH = 128;
constexpr float EPSF = 1e-6f;
constexpr float INV_LN2 = 1.4426950408889634f;
}

typedef short short8 __attribute__((ext_vector_type(8)));
typedef float f32x16 __attribute__((ext_vector_type(16)));

__device__ __forceinline__ unsigned short f2bf(float x) {
  unsigned int u = __float_as_uint(x);
  unsigned int r = (u + 0x7fffu + ((u >> 16) & 1u)) >> 16;   // RNE, finite inputs
  return (unsigned short)r;
}

// ---------------- kernel 1: convert q,k -> bf16, V^T bf16, fused gate partials ----
// 512 blocks: j0 = (b&31)*64, d0 = ((b>>5)&1)*64, h = b>>6; pidx = b>>5 (0..15)
// partial[(pidx*16 + n)*S + t] = sum over this block's 3*64 dims of gate n, row t
__global__ __launch_bounds__(256) void convert_kernel(
    const float* __restrict__ q, const float* __restrict__ k, const float* __restrict__ v,
    const float* __restrict__ Wi, const float* __restrict__ Wf,
    unsigned short* __restrict__ qb, unsigned short* __restrict__ kb,
    unsigned short* __restrict__ vt, float* __restrict__ partial)
{
  __shared__ float Qs[64][65], Ks[64][65], Vs[64][65];
  __shared__ float Wlds[3][64][16];
  __shared__ float red[64][4][17];
  const int b = blockIdx.x;
  const int j0 = (b & 31) * 64;
  const int d0 = ((b >> 5) & 1) * 64;
  const int h  = b >> 6;
  const int pidx = b >> 5;
  const int tid = threadIdx.x;
  const int c = tid & 63, r4 = tid >> 6;

  #pragma unroll
  for (int rr = 0; rr < 16; ++rr) {
    int r = r4*16 + rr;
    size_t off = (size_t)(j0 + r)*E + h*DH + d0 + c;
    float qv = q[off], kv = k[off], vv = v[off];
    qb[off] = f2bf(qv); kb[off] = f2bf(kv);
    Qs[r][c] = qv; Ks[r][c] = kv; Vs[r][c] = vv;
  }
  for (int idx = tid; idx < 3*64*16; idx += 256) {
    int p = idx >> 10, rem = idx & 1023;
    int dd = rem >> 4, n = rem & 15;
    int e = p*E + h*DH + d0 + dd;
    Wlds[p][dd][n] = (n < 8) ? Wi[e*NH + n] : Wf[e*NH + (n-8)];
  }
  __syncthreads();

  // V^T (bf16) from LDS
  #pragma unroll
  for (int rr = 0; rr < 16; ++rr) {
    int r = r4*16 + rr;
    vt[(size_t)(h*DH + d0 + r)*S + j0 + c] = f2bf(Vs[c][r]);
  }

  // gate partials: thread = (row = tid>>2, seg = tid&3 -> 16 dims)
  {
    const int row = tid >> 2, seg = tid & 3;
    float acc[16];
    #pragma unroll
    for (int n = 0; n < 16; ++n) acc[n] = 0.f;
    #pragma unroll
    for (int p = 0; p < 3; ++p) {
      const float (*Xp)[65] = (p == 0) ? Qs : (p == 1) ? Ks : Vs;
      #pragma unroll
      for (int d2 = 0; d2 < 16; ++d2) {
        int dd = seg*16 + d2;
        float x = Xp[row][dd];
        const float* wrow = &Wlds[p][dd][0];
        #pragma unroll
        for (int n = 0; n < 16; ++n) acc[n] = fmaf(x, wrow[n], acc[n]);
      }
    }
    #pragma unroll
    for (int n = 0; n < 16; ++n) red[row][seg][n] = acc[n];
  }
  __syncthreads();
  if (tid < 64) {
    const int row = tid;
    #pragma unroll
    for (int n = 0; n < 16; ++n) {
      float s = red[row][0][n] + red[row][1][n] + red[row][2][n] + red[row][3][n];
      partial[(size_t)(pidx*16 + n)*S + j0 + row] = s;
    }
  }
}

// ---------------- kernel 2: combine partials + bias + logsig + scans ----------------
__global__ __launch_bounds__(256) void scan_kernel(
    const float* __restrict__ partial,
    const float* __restrict__ bi, const float* __restrict__ bfg,
    float* __restrict__ a2_out, float* __restrict__ m2_out)
{
  const int h = blockIdx.x, tid = threadIdx.x;
  const int lane = tid & 63, wv = tid >> 6;
  constexpr int PER = S / 256;  // 8
  const int bt = tid * PER;
  __shared__ float wred[4], wmax[4];

  float ipv[PER], c[PER];
  float run = 0.f;
  #pragma unroll
  for (int u = 0; u < PER; u++) {
    int t = bt + u;
    float ip = bi[h], fp = bfg[h];
    #pragma unroll
    for (int p = 0; p < 16; ++p) {
      ip += partial[(size_t)(p*16 + h)*S + t];
      fp += partial[(size_t)(p*16 + 8 + h)*S + t];
    }
    ipv[u] = ip;
    float ls = fminf(fp, 0.f) - log1pf(__expf(-fabsf(fp)));
    run += ls; c[u] = run;
  }
  // wave inclusive scan (sum)
  float s = run;
  #pragma unroll
  for (int off = 1; off < 64; off <<= 1) {
    float t = __shfl_up(s, off);
    if (lane >= off) s += t;
  }
  if (lane == 63) wred[wv] = s;
  __syncthreads();
  float wpre = 0.f;
  for (int i = 0; i < wv; i++) wpre += wred[i];
  const float excl = wpre + (s - run);

  float av[PER], mloc[PER];
  float lm = -INFINITY;
  #pragma unroll
  for (int u = 0; u < PER; u++) {
    c[u] += excl;
    av[u] = ipv[u] - c[u];
    lm = fmaxf(lm, av[u]);
    mloc[u] = lm;
  }
  // wave inclusive scan (max)
  float sm_ = lm;
  #pragma unroll
  for (int off = 1; off < 64; off <<= 1) {
    float t = __shfl_up(sm_, off);
    if (lane >= off) sm_ = fmaxf(sm_, t);
  }
  if (lane == 63) wmax[wv] = sm_;
  __syncthreads();
  float wpm = -INFINITY;
  for (int i = 0; i < wv; i++) wpm = fmaxf(wpm, wmax[i]);
  float prev = __shfl_up(sm_, 1);
  if (lane == 0) prev = -INFINITY;
  const float exclm = fmaxf(wpm, prev);
  #pragma unroll
  for (int u = 0; u < PER; u++) {
    float m = fmaxf(exclm, mloc[u]);
    a2_out[h*S + bt + u] = av[u] * INV_LN2;
    m2_out[h*S + bt + u] = m * INV_LN2;
  }
}

// ---------------- kernel 3: MFMA causal decay-attention + LN ----------------
// 512 blocks: head = b&7 (XCD-affine), qt = 63 - (b>>3) (longest first)
// K/V chunks staged in LDS (xor-swizzled 16B blocks), register prefetch of next chunk
__global__ __launch_bounds__(256, 2) void attn_kernel(
    const unsigned short* __restrict__ qb, const unsigned short* __restrict__ kb,
    const unsigned short* __restrict__ vt,
    const float* __restrict__ a2g, const float* __restrict__ m2g,
    const float* __restrict__ ln, float* __restrict__ out)
{
  const int qt = 63 - (int)(blockIdx.x >> 3);
  const int h  = blockIdx.x & 7;
  const int tid = threadIdx.x;
  const int w = tid >> 6, lane = tid & 63, l31 = lane & 31, half = lane >> 5;
  const int qi0 = qt * 32;
  const int niter = (qt + 4) >> 2;
  const int jcol_off = 32*w + l31;

  __shared__ short Klds[128*128];   // row stride 128 shorts (256B), col16 ^= row&15
  __shared__ short Vlds[128*128];
  __shared__ short Psm[32*136];     // row stride 136 shorts (272B, 16B-aligned)
  __shared__ float mrow[32];
  float* Hs = (float*)Klds;         // epilogue overlay, stride 132 floats

  if (tid < 32) mrow[tid] = m2g[h*S + qi0 + tid];

  short8 qf[8];
  #pragma unroll
  for (int s = 0; s < 8; ++s)
    qf[s] = *reinterpret_cast<const short8*>(
        qb + (size_t)(qi0 + l31)*E + h*DH + 16*s + 8*half);

  __syncthreads();
  float mreg[16];
  #pragma unroll
  for (int r = 0; r < 16; ++r) mreg[r] = mrow[(r&3) + 8*(r>>2) + 4*half];

  f32x16 acc = {0,0,0,0,0,0,0,0,0,0,0,0,0,0,0,0};

  int4 kpre[8], vpre[8];
  // prefetch chunk 0
  #pragma unroll
  for (int u = 0; u < 8; ++u) {
    int flat = u*256 + tid, row = flat >> 4, c16 = flat & 15;
    kpre[u] = *reinterpret_cast<const int4*>(kb + (size_t)(row)*E + h*DH + c16*8);
    vpre[u] = *reinterpret_cast<const int4*>(vt + (size_t)(h*DH + row)*S + c16*8);
  }

  const int kq_row = 32*w + l31;                 // K/V LDS row for fragments
  const int kq_swz = (kq_row & 15);

  for (int jt = 0; jt < niter; ++jt) {
    const int j0 = jt * 128;
    __syncthreads();                             // prev readers of K/V/Ps done
    // commit prefetched chunk to LDS (xor-swizzled 16B blocks)
    #pragma unroll
    for (int u = 0; u < 8; ++u) {
      int flat = u*256 + tid, row = flat >> 4, c16 = flat & 15;
      int sw = (c16 ^ (row & 15)) * 8;
      *reinterpret_cast<int4*>(&Klds[row*128 + sw]) = kpre[u];
      *reinterpret_cast<int4*>(&Vlds[row*128 + sw]) = vpre[u];
    }
    const float ajv = a2g[h*S + j0 + jcol_off];  // issue early
    // prefetch next chunk
    {
      const int jn = (jt + 1 < niter) ? (jt + 1) * 128 : j0;
      #pragma unroll
      for (int u = 0; u < 8; ++u) {
        int flat = u*256 + tid, row = flat >> 4, c16 = flat & 15;
        kpre[u] = *reinterpret_cast<const int4*>(kb + (size_t)(jn + row)*E + h*DH + c16*8);
        vpre[u] = *reinterpret_cast<const int4*>(vt + (size_t)(h*DH + row)*S + jn + c16*8);
      }
    }
    __syncthreads();                             // staged chunk visible

    // QK^T
    f32x16 qk = {0,0,0,0,0,0,0,0,0,0,0,0,0,0,0,0};
    #pragma unroll
    for (int s = 0; s < 8; ++s) {
      short8 kf = *reinterpret_cast<const short8*>(
          &Klds[kq_row*128 + ((2*s + half) ^ kq_swz) * 8]);
      qk = __builtin_amdgcn_mfma_f32_32x32x16_bf16(qf[s], kf, qk, 0, 0, 0);
    }
    // P = mask * qk * 2^(a2_j - m2_i)
    const int jcol = j0 + jcol_off;
    #pragma unroll
    for (int r = 0; r < 16; ++r) {
      const int iloc = (r&3) + 8*(r>>2) + 4*half;
      float d = fminf(ajv - mreg[r], 0.f);
      float pv = (jcol <= qi0 + iloc) ? qk[r] * exp2f(d) : 0.f;
      Psm[iloc*136 + jcol_off] = (short)f2bf(pv);
    }
    __syncthreads();                             // Ps visible

    // P @ V
    #pragma unroll
    for (int s = 0; s < 8; ++s) {
      short8 pf = *reinterpret_cast<const short8*>(&Psm[l31*136 + 16*s + 8*half]);
      short8 vf = *reinterpret_cast<const short8*>(
          &Vlds[kq_row*128 + ((2*s + half) ^ kq_swz) * 8]);
      acc = __builtin_amdgcn_mfma_f32_32x32x16_bf16(pf, vf, acc, 0, 0, 0);
    }
  }

  // epilogue: LN over DH (normalizer is a per-row positive scale -> cancels)
  __syncthreads();
  #pragma unroll
  for (int r = 0; r < 16; ++r)
    Hs[((r&3) + 8*(r>>2) + 4*half)*132 + 32*w + l31] = acc[r];
  __syncthreads();
  {
    const int row = tid >> 3, seg = tid & 7;
    float vals[16];
    #pragma unroll
    for (int c4 = 0; c4 < 4; ++c4) {
      float4 v4 = *reinterpret_cast<const float4*>(&Hs[row*132 + seg*16 + c4*4]);
      vals[c4*4+0]=v4.x; vals[c4*4+1]=v4.y; vals[c4*4+2]=v4.z; vals[c4*4+3]=v4.w;
    }
    float s1 = 0.f, s2 = 0.f;
    #pragma unroll
    for (int c = 0; c < 16; ++c) { s1 += vals[c]; s2 = fmaf(vals[c], vals[c], s2); }
    #pragma unroll
    for (int off = 1; off < 8; off <<= 1) {
      s1 += __shfl_xor(s1, off);
      s2 += __shfl_xor(s2, off);
    }
    const float mu = s1 * (1.f/128.f);
    float var = fmaxf(s2 * (1.f/128.f) - mu*mu, 0.f);
    const float rs = rsqrtf(var + EPSF);
    const size_t ob = (size_t)(qi0 + row)*E + h*DH + seg*16;
    #pragma unroll
    for (int c = 0; c < 16; ++c)
      out[ob + c] = (vals[c] - mu) * rs * ln[h*DH + seg*16 + c];
  }
}

extern "C" void kernel_launch(void* const* d_in, const int* in_sizes, int n_in,
                              void* d_out, int out_size, void* d_ws, size_t ws_size,
                              hipStream_t stream) {
  const float* q  = (const float*)d_in[0];
  const float* k  = (const float*)d_in[1];
  const float* v  = (const float*)d_in[2];
  const float* Wi = (const float*)d_in[3];
  const float* bi = (const float*)d_in[4];
  const float* Wf = (const float*)d_in[5];
  const float* bf = (const float*)d_in[6];
  const float* ln = (const float*)d_in[7];
  float* out = (float*)d_out;

  // ws: qb 4MB | kb 4MB | vt 4MB | partial 2MB | a2 64KB | m2 64KB  (~14.2 MB)
  char* base = (char*)d_ws;
  unsigned short* qb = (unsigned short*)(base);
  unsigned short* kb = (unsigned short*)(base + (size_t)S*E*2);
  unsigned short* vt = (unsigned short*)(base + (size_t)S*E*4);
  float* partial = (float*)(base + (size_t)S*E*6);
  float* a2 = (float*)(base + (size_t)S*E*6 + (size_t)256*S*4);
  float* m2 = a2 + NH*S;

  convert_kernel<<<dim3(512), dim3(256), 0, stream>>>(q, k, v, Wi, Wf, qb, kb, vt, partial);
  scan_kernel<<<dim3(NH), dim3(256), 0, stream>>>(partial, bi, bf, a2, m2);
  attn_kernel<<<dim3(512), dim3(256), 0, stream>>>(qb, kb, vt, a2, m2, ln, out);
}

// Round 6
// 159.585 us; speedup vs baseline: 1.5833x; 1.5833x over previous
//
#include <hip/hip_runtime.h>
#include <math.h>

namespace {
constexpr int S  = 2048;
constexpr int E  = 1024;
constexpr int NH = 8;
constexpr int DH = 128;
constexpr float EPSF = 1e-6f;
constexpr float INV_LN2 = 1.4426950408889634f;
}

typedef short short8 __attribute__((ext_vector_type(8)));
typedef float f32x16 __attribute__((ext_vector_type(16)));
typedef float f32x4  __attribute__((ext_vector_type(4)));

__device__ __forceinline__ unsigned short f2bf(float x) {
  unsigned int u = __float_as_uint(x);
  unsigned int r = (u + 0x7fffu + ((u >> 16) & 1u)) >> 16;   // RNE, finite inputs
  return (unsigned short)r;
}

// async 16B/lane global->LDS: LDS dest = wave-uniform base + lane*16
__device__ __forceinline__ void async_copy16(const void* g, void* l) {
  __builtin_amdgcn_global_load_lds(
      (const __attribute__((address_space(1))) unsigned int*)g,
      (__attribute__((address_space(3))) unsigned int*)l, 16, 0, 0);
}

// ---------------- kernel 1: V^T bf16 + q,k cast + W^T ----------------
// blocks 0..511: V-transpose 64x64 tiles; 512..1023: q/k cast; 1024: wt2
__global__ __launch_bounds__(256) void convert_kernel(
    const float* __restrict__ q, const float* __restrict__ k, const float* __restrict__ v,
    const float* __restrict__ Wi, const float* __restrict__ Wf,
    unsigned short* __restrict__ qb, unsigned short* __restrict__ kb,
    unsigned short* __restrict__ vt, unsigned short* __restrict__ wt2)
{
  const int b = blockIdx.x;
  const int tid = threadIdx.x;
  if (b < 512) {
    __shared__ float Ts[64][65];
    const int j0 = (b & 31) * 64;
    const int d0 = ((b >> 5) & 1) * 64;
    const int h  = b >> 6;
    const int c = tid & 63, r4 = tid >> 6;
    #pragma unroll
    for (int rr = 0; rr < 16; ++rr) {
      int r = r4*16 + rr;
      Ts[r][c] = v[(size_t)(j0 + r)*E + h*DH + d0 + c];
    }
    __syncthreads();
    #pragma unroll
    for (int rr = 0; rr < 16; ++rr) {
      int r = r4*16 + rr;
      vt[(size_t)(h*DH + d0 + r)*S + j0 + c] = f2bf(Ts[c][r]);
    }
  } else if (b < 1024) {
    const int bb = b - 512;                       // 0..511
    constexpr int N4 = S*E/4;                     // 524288 float4 per tensor
    const float4* src = (bb < 256) ? (const float4*)q : (const float4*)k;
    ushort4* dst = (bb < 256) ? (ushort4*)qb : (ushort4*)kb;
    const int b0 = (bb & 255);
    for (int i = b0*256 + tid; i < N4; i += 256*256) {
      float4 x = src[i];
      ushort4 o;
      o.x = f2bf(x.x); o.y = f2bf(x.y); o.z = f2bf(x.z); o.w = f2bf(x.w);
      dst[i] = o;
    }
  } else {
    // wt2[n][e] = W[e][n], n<8 -> Wi, else Wf ; 16 x 3072
    for (int idx = tid; idx < 16*3*E; idx += 256) {
      int n = idx / (3*E), e = idx - n*(3*E);
      float val = (n < 8) ? Wi[e*NH + n] : Wf[e*NH + (n-8)];
      wt2[idx] = f2bf(val);
    }
  }
}

// ---------------- kernel 2: gate partial GEMM via MFMA ----------------
// grid (32,3): Mtile x source; partial[(p*16+n)*S + t]
__global__ __launch_bounds__(256) void gates_kernel(
    const float* __restrict__ q, const float* __restrict__ k, const float* __restrict__ v,
    const unsigned short* __restrict__ wt2, float* __restrict__ partial)
{
  const int mt = blockIdx.x, p = blockIdx.y;
  const float* src = (p == 0) ? q : (p == 1) ? k : v;
  const int wv = threadIdx.x >> 6, lane = threadIdx.x & 63;
  const int m0 = (mt*4 + wv)*16;
  const int tr = lane & 15;
  const int ks = (lane >> 4) * 8;
  f32x4 acc = {0.f, 0.f, 0.f, 0.f};
  for (int e0 = 0; e0 < E; e0 += 32) {
    const float* ap = src + (size_t)(m0 + tr)*E + e0 + ks;
    float4 a0 = *reinterpret_cast<const float4*>(ap);
    float4 a1 = *reinterpret_cast<const float4*>(ap + 4);
    short8 af;
    af[0] = (short)f2bf(a0.x); af[1] = (short)f2bf(a0.y);
    af[2] = (short)f2bf(a0.z); af[3] = (short)f2bf(a0.w);
    af[4] = (short)f2bf(a1.x); af[5] = (short)f2bf(a1.y);
    af[6] = (short)f2bf(a1.z); af[7] = (short)f2bf(a1.w);
    short8 bf8 = *reinterpret_cast<const short8*>(wt2 + (size_t)tr*(3*E) + p*E + e0 + ks);
    acc = __builtin_amdgcn_mfma_f32_16x16x32_bf16(af, bf8, acc, 0, 0, 0);
  }
  const int n = lane & 15, rbase = (lane >> 4) * 4;
  #pragma unroll
  for (int r = 0; r < 4; ++r)
    partial[(size_t)(p*16 + n)*S + m0 + rbase + r] = acc[r];
}

// ---------------- kernel 3: combine partials + bias + logsig + scans ----------------
__global__ __launch_bounds__(256) void scan_kernel(
    const float* __restrict__ partial,
    const float* __restrict__ bi, const float* __restrict__ bfg,
    float* __restrict__ a2_out, float* __restrict__ m2_out)
{
  const int h = blockIdx.x, tid = threadIdx.x;
  const int lane = tid & 63, wv = tid >> 6;
  constexpr int PER = S / 256;  // 8
  const int bt = tid * PER;
  __shared__ float wred[4], wmax[4];

  float ipv[PER], c[PER];
  float run = 0.f;
  #pragma unroll
  for (int u = 0; u < PER; u++) {
    int t = bt + u;
    float ip = bi[h], fp = bfg[h];
    #pragma unroll
    for (int p = 0; p < 3; ++p) {
      ip += partial[(size_t)(p*16 + h)*S + t];
      fp += partial[(size_t)(p*16 + 8 + h)*S + t];
    }
    ipv[u] = ip;
    float ls = fminf(fp, 0.f) - log1pf(__expf(-fabsf(fp)));
    run += ls; c[u] = run;
  }
  float s = run;
  #pragma unroll
  for (int off = 1; off < 64; off <<= 1) {
    float t = __shfl_up(s, off);
    if (lane >= off) s += t;
  }
  if (lane == 63) wred[wv] = s;
  __syncthreads();
  float wpre = 0.f;
  for (int i = 0; i < wv; i++) wpre += wred[i];
  const float excl = wpre + (s - run);

  float av[PER], mloc[PER];
  float lm = -INFINITY;
  #pragma unroll
  for (int u = 0; u < PER; u++) {
    c[u] += excl;
    av[u] = ipv[u] - c[u];
    lm = fmaxf(lm, av[u]);
    mloc[u] = lm;
  }
  float sm_ = lm;
  #pragma unroll
  for (int off = 1; off < 64; off <<= 1) {
    float t = __shfl_up(sm_, off);
    if (lane >= off) sm_ = fmaxf(sm_, t);
  }
  if (lane == 63) wmax[wv] = sm_;
  __syncthreads();
  float wpm = -INFINITY;
  for (int i = 0; i < wv; i++) wpm = fmaxf(wpm, wmax[i]);
  float prev = __shfl_up(sm_, 1);
  if (lane == 0) prev = -INFINITY;
  const float exclm = fmaxf(wpm, prev);
  #pragma unroll
  for (int u = 0; u < PER; u++) {
    float m = fmaxf(exclm, mloc[u]);
    a2_out[h*S + bt + u] = av[u] * INV_LN2;
    m2_out[h*S + bt + u] = m * INV_LN2;
  }
}

// ---------------- kernel 4: MFMA causal decay-attention + LN ----------------
// 512 blocks: head = b&7 (XCD-affine), qt = 63 - (b>>3) (longest first)
// K/V staged via async global_load_lds into XOR-swizzled LDS (no VGPR cost)
__global__ __launch_bounds__(256, 2) void attn_kernel(
    const unsigned short* __restrict__ qb, const unsigned short* __restrict__ kb,
    const unsigned short* __restrict__ vt,
    const float* __restrict__ a2g, const float* __restrict__ m2g,
    const float* __restrict__ ln, float* __restrict__ out)
{
  const int qt = 63 - (int)(blockIdx.x >> 3);
  const int h  = blockIdx.x & 7;
  const int tid = threadIdx.x;
  const int w = tid >> 6, lane = tid & 63, l31 = lane & 31, half = lane >> 5;
  const int qi0 = qt * 32;
  const int niter = (qt + 4) >> 2;
  const int jcol_off = 32*w + l31;

  __shared__ short Klds[128*128];   // 16B block (row,c): idx = row*16 + (c ^ (row&15))
  __shared__ short Vlds[128*128];   // same swizzle; row = d, cols = j
  __shared__ short Psm[32*136];
  __shared__ float mrow[32];
  float* Hs = (float*)Klds;         // epilogue overlay, stride 132 floats

  if (tid < 32) mrow[tid] = m2g[h*S + qi0 + tid];

  short8 qf[8];
  #pragma unroll
  for (int s = 0; s < 8; ++s)
    qf[s] = *reinterpret_cast<const short8*>(
        qb + (size_t)(qi0 + l31)*E + h*DH + 16*s + 8*half);

  __syncthreads();
  float mreg[16];
  #pragma unroll
  for (int r = 0; r < 16; ++r) mreg[r] = mrow[(r&3) + 8*(r>>2) + 4*half];

  f32x16 acc = {0,0,0,0,0,0,0,0,0,0,0,0,0,0,0,0};

  const int lrow4 = lane >> 4;      // row within 4-row group per staging instr
  const int jb    = lane & 15;      // LDS 16B-block slot within row
  const int kq_row = 32*w + l31;
  const int kq_swz = kq_row & 15;

  for (int jt = 0; jt < niter; ++jt) {
    const int j0 = jt * 128;
    __syncthreads();                             // prev iter's K/V/Ps consumers done

    // stage K and V chunk: 8 async instrs each per wave, LDS dest contiguous,
    // global side gathers the XOR-permuted column so swizzle lands for free
    #pragma unroll
    for (int i = 0; i < 8; ++i) {
      const int ii  = w*8 + i;                   // 0..31
      const int row = ii*4 + lrow4;              // 0..127
      const int cc  = jb ^ (row & 15);
      async_copy16(kb + (size_t)(j0 + row)*E + h*DH + cc*8, &Klds[ii*512]);
      async_copy16(vt + (size_t)(h*DH + row)*S + j0 + cc*8, &Vlds[ii*512]);
    }
    const float ajv = a2g[h*S + j0 + jcol_off];
    __syncthreads();                             // vmcnt(0) drain + staged visible

    // QK^T from LDS (conflict-free swizzled b128 reads)
    f32x16 qk = {0,0,0,0,0,0,0,0,0,0,0,0,0,0,0,0};
    #pragma unroll
    for (int s = 0; s < 8; ++s) {
      short8 kf = *reinterpret_cast<const short8*>(
          &Klds[kq_row*128 + ((2*s + half) ^ kq_swz) * 8]);
      qk = __builtin_amdgcn_mfma_f32_32x32x16_bf16(qf[s], kf, qk, 0, 0, 0);
    }
    // P = mask * qk * 2^(a2_j - m2_i)
    const int jcol = j0 + jcol_off;
    #pragma unroll
    for (int r = 0; r < 16; ++r) {
      const int iloc = (r&3) + 8*(r>>2) + 4*half;
      float pv = (jcol <= qi0 + iloc) ? qk[r] * exp2f(ajv - mreg[r]) : 0.f;
      Psm[iloc*136 + jcol_off] = (short)f2bf(pv);
    }
    __syncthreads();                             // Ps visible

    // P @ V from LDS
    #pragma unroll
    for (int s = 0; s < 8; ++s) {
      short8 pf = *reinterpret_cast<const short8*>(&Psm[l31*136 + 16*s + 8*half]);
      short8 vf = *reinterpret_cast<const short8*>(
          &Vlds[kq_row*128 + ((2*s + half) ^ kq_swz) * 8]);
      acc = __builtin_amdgcn_mfma_f32_32x32x16_bf16(pf, vf, acc, 0, 0, 0);
    }
  }

  // epilogue: LN over DH (normalizer is a per-row positive scale -> cancels)
  __syncthreads();
  #pragma unroll
  for (int r = 0; r < 16; ++r)
    Hs[((r&3) + 8*(r>>2) + 4*half)*132 + 32*w + l31] = acc[r];
  __syncthreads();
  {
    const int row = tid >> 3, seg = tid & 7;
    float vals[16];
    #pragma unroll
    for (int c4 = 0; c4 < 4; ++c4) {
      float4 v4 = *reinterpret_cast<const float4*>(&Hs[row*132 + seg*16 + c4*4]);
      vals[c4*4+0]=v4.x; vals[c4*4+1]=v4.y; vals[c4*4+2]=v4.z; vals[c4*4+3]=v4.w;
    }
    float s1 = 0.f, s2 = 0.f;
    #pragma unroll
    for (int c = 0; c < 16; ++c) { s1 += vals[c]; s2 = fmaf(vals[c], vals[c], s2); }
    #pragma unroll
    for (int off = 1; off < 8; off <<= 1) {
      s1 += __shfl_xor(s1, off);
      s2 += __shfl_xor(s2, off);
    }
    const float mu = s1 * (1.f/128.f);
    float var = fmaxf(s2 * (1.f/128.f) - mu*mu, 0.f);
    const float rs = rsqrtf(var + EPSF);
    const size_t ob = (size_t)(qi0 + row)*E + h*DH + seg*16;
    #pragma unroll
    for (int c = 0; c < 16; ++c)
      out[ob + c] = (vals[c] - mu) * rs * ln[h*DH + seg*16 + c];
  }
}

extern "C" void kernel_launch(void* const* d_in, const int* in_sizes, int n_in,
                              void* d_out, int out_size, void* d_ws, size_t ws_size,
                              hipStream_t stream) {
  const float* q  = (const float*)d_in[0];
  const float* k  = (const float*)d_in[1];
  const float* v  = (const float*)d_in[2];
  const float* Wi = (const float*)d_in[3];
  const float* bi = (const float*)d_in[4];
  const float* Wf = (const float*)d_in[5];
  const float* bf = (const float*)d_in[6];
  const float* ln = (const float*)d_in[7];
  float* out = (float*)d_out;

  // ws: qb 4MB | kb 4MB | vt 4MB | wt2 96KB | partial 384KB | a2 64KB | m2 64KB
  char* base = (char*)d_ws;
  unsigned short* qb  = (unsigned short*)(base);
  unsigned short* kb  = (unsigned short*)(base + (size_t)S*E*2);
  unsigned short* vt  = (unsigned short*)(base + (size_t)S*E*4);
  unsigned short* wt2 = (unsigned short*)(base + (size_t)S*E*6);
  float* partial = (float*)(base + (size_t)S*E*6 + 16*3*E*2);
  float* a2 = partial + (size_t)48*S;
  float* m2 = a2 + NH*S;

  convert_kernel<<<dim3(1025), dim3(256), 0, stream>>>(q, k, v, Wi, Wf, qb, kb, vt, wt2);
  gates_kernel<<<dim3(32, 3), dim3(256), 0, stream>>>(q, k, v, wt2, partial);
  scan_kernel<<<dim3(NH), dim3(256), 0, stream>>>(partial, bi, bf, a2, m2);
  attn_kernel<<<dim3(512), dim3(256), 0, stream>>>(qb, kb, vt, a2, m2, ln, out);
}

// Round 7
// 157.016 us; speedup vs baseline: 1.6092x; 1.0164x over previous
//
#include <hip/hip_runtime.h>
#include <math.h>

namespace {
constexpr int S  = 2048;
constexpr int E  = 1024;
constexpr int NH = 8;
constexpr int DH = 128;
constexpr float EPSF = 1e-6f;
constexpr float INV_LN2 = 1.4426950408889634f;
}

typedef short short8 __attribute__((ext_vector_type(8)));
typedef float f32x16 __attribute__((ext_vector_type(16)));
typedef float f32x4  __attribute__((ext_vector_type(4)));

__device__ __forceinline__ unsigned short f2bf(float x) {
  unsigned int u = __float_as_uint(x);
  unsigned int r = (u + 0x7fffu + ((u >> 16) & 1u)) >> 16;   // RNE, finite inputs
  return (unsigned short)r;
}

// async 16B/lane global->LDS: LDS dest = wave-uniform base + lane*16
__device__ __forceinline__ void async_copy16(const void* g, void* l) {
  __builtin_amdgcn_global_load_lds(
      (const __attribute__((address_space(1))) unsigned int*)g,
      (__attribute__((address_space(3))) unsigned int*)l, 16, 0, 0);
}

// ---------------- kernel 1: V^T bf16 + q,k cast + W^T ----------------
// blocks 0..511: V-transpose 64x64 tiles; 512..1023: q/k cast; 1024..1039: wt2
__global__ __launch_bounds__(256) void convert_kernel(
    const float* __restrict__ q, const float* __restrict__ k, const float* __restrict__ v,
    const float* __restrict__ Wi, const float* __restrict__ Wf,
    unsigned short* __restrict__ qb, unsigned short* __restrict__ kb,
    unsigned short* __restrict__ vt, unsigned short* __restrict__ wt2)
{
  const int b = blockIdx.x;
  const int tid = threadIdx.x;
  if (b < 512) {
    __shared__ float Ts[64][65];
    const int j0 = (b & 31) * 64;
    const int d0 = ((b >> 5) & 1) * 64;
    const int h  = b >> 6;
    const int c = tid & 63, r4 = tid >> 6;
    #pragma unroll
    for (int rr = 0; rr < 16; ++rr) {
      int r = r4*16 + rr;
      Ts[r][c] = v[(size_t)(j0 + r)*E + h*DH + d0 + c];
    }
    __syncthreads();
    #pragma unroll
    for (int rr = 0; rr < 16; ++rr) {
      int r = r4*16 + rr;
      vt[(size_t)(h*DH + d0 + r)*S + j0 + c] = f2bf(Ts[c][r]);
    }
  } else if (b < 1024) {
    const int bb = b - 512;                       // 0..511
    constexpr int N4 = S*E/4;                     // 524288 float4 per tensor
    const float4* src = (bb < 256) ? (const float4*)q : (const float4*)k;
    ushort4* dst = (bb < 256) ? (ushort4*)qb : (ushort4*)kb;
    const int b0 = (bb & 255);
    for (int i = b0*256 + tid; i < N4; i += 256*256) {
      float4 x = src[i];
      ushort4 o;
      o.x = f2bf(x.x); o.y = f2bf(x.y); o.z = f2bf(x.z); o.w = f2bf(x.w);
      dst[i] = o;
    }
  } else {
    const int n = b - 1024;                       // 0..15
    for (int e = tid; e < 3*E; e += 256) {
      float val = (n < 8) ? Wi[e*NH + n] : Wf[e*NH + (n-8)];
      wt2[(size_t)n*(3*E) + e] = f2bf(val);
    }
  }
}

// ---------------- kernel 2: gate GEMM -> ipre, lsf directly ----------------
// 32 blocks x 4 waves = 128 M-tiles of 16 rows
__global__ __launch_bounds__(256) void gates_kernel(
    const float* __restrict__ q, const float* __restrict__ k, const float* __restrict__ v,
    const unsigned short* __restrict__ wt2,
    const float* __restrict__ bi, const float* __restrict__ bfg,
    float* __restrict__ ipre, float* __restrict__ lsf)
{
  const int wv = threadIdx.x >> 6, lane = threadIdx.x & 63;
  const int m0 = (blockIdx.x*4 + wv)*16;
  const int tr = lane & 15;
  const int ks = (lane >> 4) * 8;
  f32x4 acc = {0.f, 0.f, 0.f, 0.f};
  const float* srcs[3] = {q, k, v};
  #pragma unroll
  for (int p = 0; p < 3; ++p) {
    const float* src = srcs[p];
    for (int e0 = 0; e0 < E; e0 += 32) {
      const float* ap = src + (size_t)(m0 + tr)*E + e0 + ks;
      float4 a0 = *reinterpret_cast<const float4*>(ap);
      float4 a1 = *reinterpret_cast<const float4*>(ap + 4);
      short8 af;
      af[0] = (short)f2bf(a0.x); af[1] = (short)f2bf(a0.y);
      af[2] = (short)f2bf(a0.z); af[3] = (short)f2bf(a0.w);
      af[4] = (short)f2bf(a1.x); af[5] = (short)f2bf(a1.y);
      af[6] = (short)f2bf(a1.z); af[7] = (short)f2bf(a1.w);
      short8 bf8 = *reinterpret_cast<const short8*>(wt2 + (size_t)tr*(3*E) + p*E + e0 + ks);
      acc = __builtin_amdgcn_mfma_f32_16x16x32_bf16(af, bf8, acc, 0, 0, 0);
    }
  }
  const int n = lane & 15, rbase = (lane >> 4) * 4;
  #pragma unroll
  for (int r = 0; r < 4; ++r) {
    int t = m0 + rbase + r;
    float val = acc[r];
    if (n < 8) {
      ipre[n*S + t] = val + bi[n];
    } else {
      float fp = val + bfg[n-8];
      lsf[(n-8)*S + t] = fminf(fp, 0.f) - log1pf(__expf(-fabsf(fp)));
    }
  }
}

// ---------------- kernel 3: per-head scans -> a2 = a/ln2, m2 = m/ln2 ----------------
__global__ __launch_bounds__(256) void scan_kernel(
    const float* __restrict__ ipre, const float* __restrict__ lsf,
    float* __restrict__ a2_out, float* __restrict__ m2_out)
{
  const int h = blockIdx.x, tid = threadIdx.x;
  const int lane = tid & 63, wv = tid >> 6;
  constexpr int PER = S / 256;  // 8
  const int base = h*S + tid*PER;
  __shared__ float wred[4], wmax[4];

  float c[PER];
  float run = 0.f;
  #pragma unroll
  for (int u = 0; u < PER; u++) { run += lsf[base+u]; c[u] = run; }
  float s = run;
  #pragma unroll
  for (int off = 1; off < 64; off <<= 1) {
    float t = __shfl_up(s, off);
    if (lane >= off) s += t;
  }
  if (lane == 63) wred[wv] = s;
  __syncthreads();
  float wpre = 0.f;
  for (int i = 0; i < wv; i++) wpre += wred[i];
  const float excl = wpre + (s - run);

  float av[PER], mloc[PER];
  float lm = -INFINITY;
  #pragma unroll
  for (int u = 0; u < PER; u++) {
    c[u] += excl;
    av[u] = ipre[base+u] - c[u];
    lm = fmaxf(lm, av[u]);
    mloc[u] = lm;
  }
  float sm_ = lm;
  #pragma unroll
  for (int off = 1; off < 64; off <<= 1) {
    float t = __shfl_up(sm_, off);
    if (lane >= off) sm_ = fmaxf(sm_, t);
  }
  if (lane == 63) wmax[wv] = sm_;
  __syncthreads();
  float wpm = -INFINITY;
  for (int i = 0; i < wv; i++) wpm = fmaxf(wpm, wmax[i]);
  float prev = __shfl_up(sm_, 1);
  if (lane == 0) prev = -INFINITY;
  const float exclm = fmaxf(wpm, prev);
  #pragma unroll
  for (int u = 0; u < PER; u++) {
    float m = fmaxf(exclm, mloc[u]);
    a2_out[base+u] = av[u] * INV_LN2;
    m2_out[base+u] = m * INV_LN2;
  }
}

// ---------------- kernel 4: MFMA causal decay-attention, split-K ----------------
// blocks 0..511: (h=b&7, qt=63-(b>>3), part 0); 512..767: part 1 for qt>=32.
// qt>=32 rows are split into two j-ranges; raw O parts -> ws (normalizer cancels,
// both parts share basis exp2(a2_j - m2_i)); combine kernel adds + LN.
__global__ __launch_bounds__(256, 2) void attn_kernel(
    const unsigned short* __restrict__ qb, const unsigned short* __restrict__ kb,
    const unsigned short* __restrict__ vt,
    const float* __restrict__ a2g, const float* __restrict__ m2g,
    const float* __restrict__ ln, float* __restrict__ opart, float* __restrict__ out)
{
  const int b = blockIdx.x;
  int h, qt, part;
  if (b < 512) { h = b & 7; qt = 63 - (b >> 3); part = 0; }
  else { int i = b - 512; h = i & 7; qt = 63 - (i >> 3); part = 1; }  // qt 32..63
  const int nspl = (qt >= 32) ? 2 : 1;
  const int N = (qt + 4) >> 2;
  const int jt_lo = (part == 1) ? (N >> 1) : 0;
  const int jt_hi = (nspl == 2 && part == 0) ? (N >> 1) : N;

  const int tid = threadIdx.x;
  const int w = tid >> 6, lane = tid & 63, l31 = lane & 31, half = lane >> 5;
  const int qi0 = qt * 32;
  const int jcol_off = 32*w + l31;

  __shared__ short Klds[128*128];   // 16B block (row,c): idx = row*16 + (c ^ (row&15))
  __shared__ short Vlds[128*128];
  __shared__ short Psm[32*136];
  __shared__ float mrow[32];
  float* Hs = (float*)Klds;         // epilogue overlay, stride 132 floats

  if (tid < 32) mrow[tid] = m2g[h*S + qi0 + tid];

  short8 qf[8];
  #pragma unroll
  for (int s = 0; s < 8; ++s)
    qf[s] = *reinterpret_cast<const short8*>(
        qb + (size_t)(qi0 + l31)*E + h*DH + 16*s + 8*half);

  __syncthreads();
  float mreg[16];
  #pragma unroll
  for (int r = 0; r < 16; ++r) mreg[r] = mrow[(r&3) + 8*(r>>2) + 4*half];

  f32x16 acc = {0,0,0,0,0,0,0,0,0,0,0,0,0,0,0,0};

  const int lrow4 = lane >> 4;
  const int jb    = lane & 15;
  const int kq_row = 32*w + l31;
  const int kq_swz = kq_row & 15;

  for (int jt = jt_lo; jt < jt_hi; ++jt) {
    const int j0 = jt * 128;
    __syncthreads();                             // prev iter's K/V/Ps consumers done
    #pragma unroll
    for (int i = 0; i < 8; ++i) {
      const int ii  = w*8 + i;
      const int row = ii*4 + lrow4;
      const int cc  = jb ^ (row & 15);
      async_copy16(kb + (size_t)(j0 + row)*E + h*DH + cc*8, &Klds[ii*512]);
      async_copy16(vt + (size_t)(h*DH + row)*S + j0 + cc*8, &Vlds[ii*512]);
    }
    const float ajv = a2g[h*S + j0 + jcol_off];
    __syncthreads();                             // staged visible

    f32x16 qk = {0,0,0,0,0,0,0,0,0,0,0,0,0,0,0,0};
    #pragma unroll
    for (int s = 0; s < 8; ++s) {
      short8 kf = *reinterpret_cast<const short8*>(
          &Klds[kq_row*128 + ((2*s + half) ^ kq_swz) * 8]);
      qk = __builtin_amdgcn_mfma_f32_32x32x16_bf16(qf[s], kf, qk, 0, 0, 0);
    }
    const int jcol = j0 + jcol_off;
    #pragma unroll
    for (int r = 0; r < 16; ++r) {
      const int iloc = (r&3) + 8*(r>>2) + 4*half;
      float pv = (jcol <= qi0 + iloc) ? qk[r] * exp2f(ajv - mreg[r]) : 0.f;
      Psm[iloc*136 + jcol_off] = (short)f2bf(pv);
    }
    __syncthreads();                             // Ps visible
    #pragma unroll
    for (int s = 0; s < 8; ++s) {
      short8 pf = *reinterpret_cast<const short8*>(&Psm[l31*136 + 16*s + 8*half]);
      short8 vf = *reinterpret_cast<const short8*>(
          &Vlds[kq_row*128 + ((2*s + half) ^ kq_swz) * 8]);
      acc = __builtin_amdgcn_mfma_f32_32x32x16_bf16(pf, vf, acc, 0, 0, 0);
    }
  }

  if (nspl == 2) {
    // raw O part -> ws, combine kernel finishes
    float* dst = opart + ((size_t)((qt - 32)*8 + h)*2 + part)*(32*128);
    #pragma unroll
    for (int r = 0; r < 16; ++r) {
      const int iloc = (r&3) + 8*(r>>2) + 4*half;
      dst[iloc*128 + 32*w + l31] = acc[r];
    }
    return;
  }

  // epilogue: LN over DH (normalizer is a per-row positive scale -> cancels)
  __syncthreads();
  #pragma unroll
  for (int r = 0; r < 16; ++r)
    Hs[((r&3) + 8*(r>>2) + 4*half)*132 + 32*w + l31] = acc[r];
  __syncthreads();
  {
    const int row = tid >> 3, seg = tid & 7;
    float vals[16];
    #pragma unroll
    for (int c4 = 0; c4 < 4; ++c4) {
      float4 v4 = *reinterpret_cast<const float4*>(&Hs[row*132 + seg*16 + c4*4]);
      vals[c4*4+0]=v4.x; vals[c4*4+1]=v4.y; vals[c4*4+2]=v4.z; vals[c4*4+3]=v4.w;
    }
    float s1 = 0.f, s2 = 0.f;
    #pragma unroll
    for (int c = 0; c < 16; ++c) { s1 += vals[c]; s2 = fmaf(vals[c], vals[c], s2); }
    #pragma unroll
    for (int off = 1; off < 8; off <<= 1) {
      s1 += __shfl_xor(s1, off);
      s2 += __shfl_xor(s2, off);
    }
    const float mu = s1 * (1.f/128.f);
    float var = fmaxf(s2 * (1.f/128.f) - mu*mu, 0.f);
    const float rs = rsqrtf(var + EPSF);
    const size_t ob = (size_t)(qi0 + row)*E + h*DH + seg*16;
    #pragma unroll
    for (int c = 0; c < 16; ++c)
      out[ob + c] = (vals[c] - mu) * rs * ln[h*DH + seg*16 + c];
  }
}

// ---------------- kernel 5: combine split parts + LN ----------------
// 256 blocks: one per (h, qt>=32) tile
__global__ __launch_bounds__(256) void combine_kernel(
    const float* __restrict__ opart, const float* __restrict__ ln,
    float* __restrict__ out)
{
  const int t = blockIdx.x;
  const int qt = 32 + (t >> 3);
  const int h  = t & 7;
  const float* p0 = opart + (size_t)((qt - 32)*8 + h)*2*(32*128);
  const float* p1 = p0 + 32*128;
  const int tid = threadIdx.x;
  const int row = tid >> 3, seg = tid & 7;
  float vals[16];
  #pragma unroll
  for (int c4 = 0; c4 < 4; ++c4) {
    float4 a = *reinterpret_cast<const float4*>(&p0[row*128 + seg*16 + c4*4]);
    float4 b = *reinterpret_cast<const float4*>(&p1[row*128 + seg*16 + c4*4]);
    vals[c4*4+0] = a.x + b.x; vals[c4*4+1] = a.y + b.y;
    vals[c4*4+2] = a.z + b.z; vals[c4*4+3] = a.w + b.w;
  }
  float s1 = 0.f, s2 = 0.f;
  #pragma unroll
  for (int c = 0; c < 16; ++c) { s1 += vals[c]; s2 = fmaf(vals[c], vals[c], s2); }
  #pragma unroll
  for (int off = 1; off < 8; off <<= 1) {
    s1 += __shfl_xor(s1, off);
    s2 += __shfl_xor(s2, off);
  }
  const float mu = s1 * (1.f/128.f);
  float var = fmaxf(s2 * (1.f/128.f) - mu*mu, 0.f);
  const float rs = rsqrtf(var + EPSF);
  const size_t ob = (size_t)(qt*32 + row)*E + h*DH + seg*16;
  #pragma unroll
  for (int c = 0; c < 16; ++c)
    out[ob + c] = (vals[c] - mu) * rs * ln[h*DH + seg*16 + c];
}

extern "C" void kernel_launch(void* const* d_in, const int* in_sizes, int n_in,
                              void* d_out, int out_size, void* d_ws, size_t ws_size,
                              hipStream_t stream) {
  const float* q  = (const float*)d_in[0];
  const float* k  = (const float*)d_in[1];
  const float* v  = (const float*)d_in[2];
  const float* Wi = (const float*)d_in[3];
  const float* bi = (const float*)d_in[4];
  const float* Wf = (const float*)d_in[5];
  const float* bf = (const float*)d_in[6];
  const float* ln = (const float*)d_in[7];
  float* out = (float*)d_out;

  // ws: qb 4MB | kb 4MB | vt 4MB | wt2 96KB | ipre/lsf/a2/m2 4x64KB | opart 8MB
  char* base = (char*)d_ws;
  unsigned short* qb  = (unsigned short*)(base);
  unsigned short* kb  = (unsigned short*)(base + (size_t)S*E*2);
  unsigned short* vt  = (unsigned short*)(base + (size_t)S*E*4);
  unsigned short* wt2 = (unsigned short*)(base + (size_t)S*E*6);
  float* fbase = (float*)(base + (size_t)S*E*6 + 16*3*E*2);
  float* ipre = fbase;
  float* lsf  = fbase + 1*NH*S;
  float* a2   = fbase + 2*NH*S;
  float* m2   = fbase + 3*NH*S;
  float* opart = fbase + 4*NH*S;

  convert_kernel<<<dim3(1040), dim3(256), 0, stream>>>(q, k, v, Wi, Wf, qb, kb, vt, wt2);
  gates_kernel<<<dim3(32), dim3(256), 0, stream>>>(q, k, v, wt2, bi, bf, ipre, lsf);
  scan_kernel<<<dim3(NH), dim3(256), 0, stream>>>(ipre, lsf, a2, m2);
  attn_kernel<<<dim3(768), dim3(256), 0, stream>>>(qb, kb, vt, a2, m2, ln, opart, out);
  combine_kernel<<<dim3(256), dim3(256), 0, stream>>>(opart, ln, out);
}